// Round 2
// baseline (295.072 us; speedup 1.0000x reference)
//
#include <hip/hip_runtime.h>

// Problem constants (from reference): E=1024, H=16, D=64, B=32, S=1024.
// ALGEBRA: softmax over a length-1 key axis == 1.0 exactly, so attention
// collapses: attn_out[b,s,:] = Wo @ (Wv @ (W_heat @ heat[b] + b_heat) + bv) + bo
// (independent of s; the img projection / Q / K path is dead code).
// Final: out[b,s,:] = LayerNorm(img_feat[b,s,:] + a[b,:]) * gamma + beta.
// DTYPE: all inputs/outputs are float32 (reference uses jnp.float32; R1's NaN
// came from misreading fp32 buffers as bf16).

#define E_DIM 1024
#define B_DIM 32
#define S_DIM 1024

// ---- GEMV stage: y[b,e] = dot(W[e,:], x[b,:]) + bias[e] -------------------
// One 64-lane wave per output element; 4 waves (256 threads) per block.
// Each lane reads float4 (16 B) -> fully coalesced 1 KiB per wave-instruction.
__global__ __launch_bounds__(256) void gemv_f32(
        const float* __restrict__ W,    // [E,E] row-major
        const float* __restrict__ bias, // [E]
        const float* __restrict__ x,    // [B,E]
        float* __restrict__ y) {        // [B,E]
    int wave = threadIdx.x >> 6;
    int lane = threadIdx.x & 63;
    int out_idx = (blockIdx.x << 2) + wave;      // [0, B*E)
    int b = out_idx >> 10;                       // / E
    int e = out_idx & (E_DIM - 1);
    const float4* w4 = reinterpret_cast<const float4*>(W + (size_t)e * E_DIM);
    const float4* x4 = reinterpret_cast<const float4*>(x + (size_t)b * E_DIM);
    float acc = 0.f;
    #pragma unroll
    for (int p = 0; p < 4; ++p) {
        float4 wv = w4[p * 64 + lane];
        float4 xv = x4[p * 64 + lane];
        acc += wv.x * xv.x + wv.y * xv.y + wv.z * xv.z + wv.w * xv.w;
    }
    #pragma unroll
    for (int off = 32; off; off >>= 1)
        acc += __shfl_down(acc, off, 64);
    if (lane == 0) y[out_idx] = acc + bias[e];
}

// ---- Fused residual-add + LayerNorm ---------------------------------------
// One block (256 threads) per row (b*S + s); 4 fp32 elements per thread
// via float4 (16 B/lane -> coalescing sweet spot).
__global__ __launch_bounds__(256) void resid_layernorm(
        const float* __restrict__ img,   // [B,S,E]
        const float* __restrict__ a,     // [B,E] (attn_out, per batch)
        const float* __restrict__ gamma, // [E]
        const float* __restrict__ beta,  // [E]
        float* __restrict__ out) {       // [B,S,E]
    const int row = blockIdx.x;          // b*S + s
    const int b = row >> 10;             // / S
    const int t = threadIdx.x;

    const float4* imgp = reinterpret_cast<const float4*>(img + (size_t)row * E_DIM);
    const float4* ap   = reinterpret_cast<const float4*>(a + (size_t)b * E_DIM);

    float4 iv = imgp[t];
    float4 av = ap[t];

    float x0 = iv.x + av.x;
    float x1 = iv.y + av.y;
    float x2 = iv.z + av.z;
    float x3 = iv.w + av.w;

    float s = x0 + x1 + x2 + x3;
    float q = x0 * x0 + x1 * x1 + x2 * x2 + x3 * x3;

    #pragma unroll
    for (int off = 32; off; off >>= 1) {
        s += __shfl_down(s, off, 64);
        q += __shfl_down(q, off, 64);
    }

    __shared__ float ssum[4], sqq[4];
    int wv = t >> 6, ln = t & 63;
    if (ln == 0) { ssum[wv] = s; sqq[wv] = q; }
    __syncthreads();
    if (t == 0) {
        float S = ssum[0] + ssum[1] + ssum[2] + ssum[3];
        float Q = sqq[0] + sqq[1] + sqq[2] + sqq[3];
        float mu = S * (1.0f / E_DIM);
        float var = Q * (1.0f / E_DIM) - mu * mu;
        ssum[0] = mu;
        sqq[0] = rsqrtf(var + 1e-5f);
    }
    __syncthreads();
    float mu = ssum[0];
    float rstd = sqq[0];

    const float4* gp = reinterpret_cast<const float4*>(gamma) + t;
    const float4* bp = reinterpret_cast<const float4*>(beta) + t;
    float4 gv = *gp, bv = *bp;

    float4 ov;
    ov.x = (x0 - mu) * rstd * gv.x + bv.x;
    ov.y = (x1 - mu) * rstd * gv.y + bv.y;
    ov.z = (x2 - mu) * rstd * gv.z + bv.z;
    ov.w = (x3 - mu) * rstd * gv.w + bv.w;

    reinterpret_cast<float4*>(out + (size_t)row * E_DIM)[t] = ov;
}

extern "C" void kernel_launch(void* const* d_in, const int* in_sizes, int n_in,
                              void* d_out, int out_size, void* d_ws, size_t ws_size,
                              hipStream_t stream) {
    // setup_inputs order:
    // 0 img_feat [B,S,E], 1 heat_feat [B,E], 2 W_img, 3 b_img, 4 W_heat, 5 b_heat,
    // 6 Wq, 7 bq, 8 Wk, 9 bk, 10 Wv, 11 bv, 12 Wo, 13 bo, 14 gamma, 15 beta
    const float* heat   = (const float*)d_in[1];
    const float* W_heat = (const float*)d_in[4];
    const float* b_heat = (const float*)d_in[5];
    const float* Wv     = (const float*)d_in[10];
    const float* bvv    = (const float*)d_in[11];
    const float* Wo     = (const float*)d_in[12];
    const float* bo     = (const float*)d_in[13];
    const float* img    = (const float*)d_in[0];
    const float* gamma  = (const float*)d_in[14];
    const float* beta   = (const float*)d_in[15];
    float* out = (float*)d_out;

    // Workspace: 3 fp32 [B,E] buffers = 384 KiB.
    float* ws = (float*)d_ws;
    float* tt = ws;                      // W_heat stage
    float* vv = ws + B_DIM * E_DIM;      // Wv stage
    float* aa = ws + 2 * B_DIM * E_DIM;  // Wo stage (attn_out rows)

    const int n_be = B_DIM * E_DIM;      // 32768
    const int gemv_blocks = n_be / 4;    // 4 outputs (waves) per block

    gemv_f32<<<gemv_blocks, 256, 0, stream>>>(W_heat, b_heat, heat, tt);
    gemv_f32<<<gemv_blocks, 256, 0, stream>>>(Wv, bvv, tt, vv);
    gemv_f32<<<gemv_blocks, 256, 0, stream>>>(Wo, bo, vv, aa);

    resid_layernorm<<<B_DIM * S_DIM, 256, 0, stream>>>(img, aa, gamma, beta, out);
}